// Round 1
// baseline (1311.506 us; speedup 1.0000x reference)
//
#include <hip/hip_runtime.h>
#include <stdint.h>

// Problem dims: T=4, B=16, C=512, H=W=16 -> N=256. heads=8, d=64.
#define BCN  (16*512*256)        // 2,097,152
#define CN   (512*256)
#define NG   64                  // T*B groups

// ---------------------------------------------------------------------------
// conv1x1 as GEMM per group g=(t*B+b): Y_g[o][n] = sum_c W[o][c]*X_g[c][n] (+bias)
// fp64 accumulation (products fp32xfp32 are exact in fp64) -> essentially exact.
// Tile: 64(o) x 64(n), K-chunk 32, 256 threads, 4x4 per thread.
// ---------------------------------------------------------------------------
template<typename IN_T>
__global__ __launch_bounds__(256)
void conv_gemm(const IN_T* __restrict__ X, const float* __restrict__ W,
               const float* __restrict__ bias, float* __restrict__ Y) {
  const int g  = blockIdx.z;
  const int o0 = blockIdx.y << 6;
  const int n0 = blockIdx.x << 6;
  const int tid = threadIdx.x;
  const int tx = tid & 15, ty = tid >> 4;

  const IN_T* __restrict__ Xg = X + (size_t)g * CN;
  float* __restrict__ Yg = Y + (size_t)g * CN;

  __shared__ double wS[32][65];   // [c][o], pad -> conflict-free stores
  __shared__ double xS[32][65];   // [c][n]

  double acc[4][4];
  #pragma unroll
  for (int i = 0; i < 4; ++i)
    #pragma unroll
    for (int j = 0; j < 4; ++j) acc[i][j] = 0.0;

  for (int c0 = 0; c0 < 512; c0 += 32) {
    #pragma unroll
    for (int i = 0; i < 8; ++i) {           // W tile: 64 o x 32 c
      int L = i * 256 + tid;
      int r = L >> 5, cc = L & 31;
      wS[cc][r] = (double)W[(size_t)(o0 + r) * 512 + c0 + cc];
    }
    #pragma unroll
    for (int i = 0; i < 8; ++i) {           // X tile: 32 c x 64 n
      int L = i * 256 + tid;
      int cc = L >> 6, nn = L & 63;
      xS[cc][nn] = (double)Xg[(size_t)(c0 + cc) * 256 + n0 + nn];
    }
    __syncthreads();
    #pragma unroll
    for (int kk = 0; kk < 32; ++kk) {
      double a[4], b[4];
      #pragma unroll
      for (int i = 0; i < 4; ++i) a[i] = wS[kk][ty + 16 * i];
      #pragma unroll
      for (int j = 0; j < 4; ++j) b[j] = xS[kk][tx + 16 * j];
      #pragma unroll
      for (int i = 0; i < 4; ++i)
        #pragma unroll
        for (int j = 0; j < 4; ++j)
          acc[i][j] += a[i] * b[j];         // v_fma_f64
    }
    __syncthreads();
  }
  #pragma unroll
  for (int i = 0; i < 4; ++i) {
    int o = o0 + ty + 16 * i;
    double bi = bias ? (double)bias[o] : 0.0;
    #pragma unroll
    for (int j = 0; j < 4; ++j)
      Yg[(size_t)o * 256 + n0 + tx + 16 * j] = (float)(acc[i][j] + bi);
  }
}

// ---------------------------------------------------------------------------
// BN training-mode stats per channel over (T,B,N) = 16384 values, fp64.
// Emits scale[c] = gamma*rsqrt(var+eps), shift[c] = beta - mean*scale.
// ---------------------------------------------------------------------------
__global__ __launch_bounds__(256)
void bn_stats(const float* __restrict__ Y, const float* __restrict__ gamma,
              const float* __restrict__ beta, double* __restrict__ stats) {
  const int c = blockIdx.x;
  const int tid = threadIdx.x;
  __shared__ double red[256];
  __shared__ double mean_sh;

  double s = 0.0;
  for (int g = 0; g < NG; ++g)
    s += (double)Y[((size_t)g * 512 + c) * 256 + tid];
  red[tid] = s; __syncthreads();
  for (int off = 128; off > 0; off >>= 1) {
    if (tid < off) red[tid] += red[tid + off];
    __syncthreads();
  }
  if (tid == 0) mean_sh = red[0] * (1.0 / 16384.0);
  __syncthreads();
  double m = mean_sh;

  double s2 = 0.0;
  for (int g = 0; g < NG; ++g) {
    double d = (double)Y[((size_t)g * 512 + c) * 256 + tid] - m;
    s2 += d * d;
  }
  red[tid] = s2; __syncthreads();
  for (int off = 128; off > 0; off >>= 1) {
    if (tid < off) red[tid] += red[tid + off];
    __syncthreads();
  }
  if (tid == 0) {
    double var = red[0] * (1.0 / 16384.0);
    double rstd = 1.0 / sqrt(var + 1e-5);
    double scale = (double)gamma[c] * rstd;
    stats[c] = scale;
    stats[512 + c] = (double)beta[c] - m * scale;
  }
}

// ---------------------------------------------------------------------------
// Multi-step LIF over T=4 (tau=2, hard reset to 0). Optional BN affine applied
// first (stats==nullptr -> identity). Writes spikes as u8 or f32.
// ---------------------------------------------------------------------------
__global__ __launch_bounds__(256)
void lif_kernel(const float* __restrict__ Y, const double* __restrict__ stats,
                double thresh, unsigned char* __restrict__ s_u8,
                float* __restrict__ s_f32) {
  const size_t idx = (size_t)blockIdx.x * 256 + threadIdx.x;   // over B*C*N
  const int c = (int)((idx >> 8) & 511);
  double scale = 1.0, shift = 0.0;
  if (stats) { scale = stats[c]; shift = stats[512 + c]; }
  double v = 0.0;
  #pragma unroll
  for (int t = 0; t < 4; ++t) {
    double z = (double)Y[(size_t)t * BCN + idx] * scale + shift;
    v = v + (z - v) * 0.5;
    bool sp = (v - thresh) >= 0.0;
    if (s_u8) s_u8[(size_t)t * BCN + idx] = sp ? 1 : 0;
    else      s_f32[(size_t)t * BCN + idx] = sp ? 1.0f : 0.0f;
    if (sp) v = 0.0;
  }
}

// ---------------------------------------------------------------------------
// kv[d][e] = sum_n k[c=h*64+d][n] * v[c=h*64+e][n]  (integer counts <= 256)
// One block per (t,b,h). Exact.
// ---------------------------------------------------------------------------
__global__ __launch_bounds__(256)
void attn_kv(const unsigned char* __restrict__ sk, const unsigned char* __restrict__ sv,
             float* __restrict__ kv) {
  const int blk = blockIdx.x;                       // g*8 + h
  const int tid = threadIdx.x;
  const size_t base = ((size_t)(blk >> 3) * 512 + (size_t)(blk & 7) * 64) * 256;
  __shared__ unsigned char kS[64][256];
  __shared__ unsigned char vS[64][256];
  const uint32_t* K32 = (const uint32_t*)(sk + base);
  const uint32_t* V32 = (const uint32_t*)(sv + base);
  uint32_t* kS32 = (uint32_t*)&kS[0][0];
  uint32_t* vS32 = (uint32_t*)&vS[0][0];
  #pragma unroll
  for (int i = 0; i < 16; ++i) {
    kS32[i * 256 + tid] = K32[i * 256 + tid];
    vS32[i * 256 + tid] = V32[i * 256 + tid];
  }
  __syncthreads();
  const int d0 = (tid >> 4) << 2, e0 = (tid & 15) << 2;
  int acc[4][4] = {};
  for (int n = 0; n < 256; ++n) {
    int k_[4], v_[4];
    #pragma unroll
    for (int i = 0; i < 4; ++i) k_[i] = kS[d0 + i][n];
    #pragma unroll
    for (int j = 0; j < 4; ++j) v_[j] = vS[e0 + j][n];
    #pragma unroll
    for (int i = 0; i < 4; ++i)
      #pragma unroll
      for (int j = 0; j < 4; ++j) acc[i][j] += k_[i] * v_[j];
  }
  float* KV = kv + (size_t)blk * 4096;
  #pragma unroll
  for (int i = 0; i < 4; ++i)
    #pragma unroll
    for (int j = 0; j < 4; ++j)
      KV[(d0 + i) * 64 + e0 + j] = (float)acc[i][j];
}

// ---------------------------------------------------------------------------
// attn[c=h*64+e][n] = 0.125 * sum_d q[c=h*64+d][n] * kv[d][e]  (exact in fp32)
// One block per (t,b,h); thread owns one n, all 64 e.
// ---------------------------------------------------------------------------
__global__ __launch_bounds__(256)
void attn_qkv(const unsigned char* __restrict__ sq, const float* __restrict__ kv,
              float* __restrict__ attn) {
  const int blk = blockIdx.x;
  const int tid = threadIdx.x;
  const size_t base = ((size_t)(blk >> 3) * 512 + (size_t)(blk & 7) * 64) * 256;
  __shared__ unsigned char qS[64][256];
  __shared__ float kvS[64][64];
  const uint32_t* Q32 = (const uint32_t*)(sq + base);
  uint32_t* qS32 = (uint32_t*)&qS[0][0];
  const float* KV = kv + (size_t)blk * 4096;
  #pragma unroll
  for (int i = 0; i < 16; ++i) {
    qS32[i * 256 + tid] = Q32[i * 256 + tid];
    (&kvS[0][0])[i * 256 + tid] = KV[i * 256 + tid];
  }
  __syncthreads();
  const int n = tid;
  float acc[64];
  #pragma unroll
  for (int e = 0; e < 64; ++e) acc[e] = 0.0f;
  for (int d = 0; d < 64; ++d) {
    float qf = (float)qS[d][n];
    #pragma unroll
    for (int e = 0; e < 64; ++e) acc[e] = fmaf(qf, kvS[d][e], acc[e]);
  }
  float* A = attn + base;
  #pragma unroll
  for (int e = 0; e < 64; ++e) A[(size_t)e * 256 + n] = acc[e] * 0.125f;
}

// ---------------------------------------------------------------------------
extern "C" void kernel_launch(void* const* d_in, const int* in_sizes, int n_in,
                              void* d_out, int out_size, void* d_ws, size_t ws_size,
                              hipStream_t stream) {
  const float* x          = (const float*)d_in[0];
  const float* q_w        = (const float*)d_in[1];
  const float* q_gamma    = (const float*)d_in[2];
  const float* q_beta     = (const float*)d_in[3];
  const float* k_w        = (const float*)d_in[4];
  const float* k_gamma    = (const float*)d_in[5];
  const float* k_beta     = (const float*)d_in[6];
  const float* v_w        = (const float*)d_in[7];
  const float* v_gamma    = (const float*)d_in[8];
  const float* v_beta     = (const float*)d_in[9];
  const float* proj_w     = (const float*)d_in[10];
  const float* proj_b     = (const float*)d_in[11];
  const float* proj_gamma = (const float*)d_in[12];
  const float* proj_beta  = (const float*)d_in[13];

  const size_t YB = (size_t)4 * BCN * sizeof(float);      // 33,554,432
  const size_t SB = (size_t)4 * BCN;                      //  8,388,608
  if (ws_size < YB + 5 * SB + 1024 * sizeof(double)) return;

  char* ws = (char*)d_ws;
  float* yA           = (float*)ws;                       // conv out / attn vals / proj out
  unsigned char* s_q  = (unsigned char*)(ws + YB);
  unsigned char* s_k  = s_q + SB;
  unsigned char* s_v  = s_k + SB;
  unsigned char* s_at = s_v + SB;
  float* kvb          = (float*)(ws + YB + 4 * SB);       // 8,388,608 B (2M floats)
  double* stats       = (double*)(ws + YB + 5 * SB);      // 1024 doubles

  dim3 gGemm(4, 8, NG);   // n-tiles, o-tiles, groups

  const float* bw[3] = {q_w, k_w, v_w};
  const float* bg[3] = {q_gamma, k_gamma, v_gamma};
  const float* bb[3] = {q_beta, k_beta, v_beta};
  unsigned char* bs[3] = {s_q, s_k, s_v};

  for (int i = 0; i < 3; ++i) {
    conv_gemm<float><<<gGemm, 256, 0, stream>>>(x, bw[i], nullptr, yA);
    bn_stats<<<512, 256, 0, stream>>>(yA, bg[i], bb[i], stats);
    lif_kernel<<<8192, 256, 0, stream>>>(yA, stats, 1.0, bs[i], nullptr);
  }

  attn_kv<<<512, 256, 0, stream>>>(s_k, s_v, kvb);
  attn_qkv<<<512, 256, 0, stream>>>(s_q, kvb, yA);
  lif_kernel<<<8192, 256, 0, stream>>>(yA, nullptr, 0.5, s_at, nullptr);

  conv_gemm<unsigned char><<<gGemm, 256, 0, stream>>>(s_at, proj_w, proj_b, yA);
  bn_stats<<<512, 256, 0, stream>>>(yA, proj_gamma, proj_beta, stats);
  lif_kernel<<<8192, 256, 0, stream>>>(yA, stats, 1.0, nullptr, (float*)d_out);
}

// Round 3
// 1058.076 us; speedup vs baseline: 1.2395x; 1.2395x over previous
//
#include <hip/hip_runtime.h>
#include <stdint.h>

// Problem dims: T=4, B=16, C=512, H=W=16 -> N=256. heads=8, d=64.
#define BCN  (16*512*256)        // 2,097,152
#define CN   (512*256)
#define NG   64                  // T*B groups

// ---------------------------------------------------------------------------
// conv1x1 as GEMM per group g: Y_g[o][n] = sum_c W[o][c]*X_g[c][n] (+bias)
// fp64 vector FMA, full fp64 accumulation -> exact vs np64 reference.
// Block 256 thr (4 waves). Tile 128(o) x 64(n), K-chunk 32, 8x4 accs/thread.
// LDS holds tiles as double (cvt at stage time). Register-prefetch dbuf.
// Read patterns: a-reads broadcast over 16-lane groups (2-way bank = free),
// b-reads broadcast x4, conflict-free.
// ---------------------------------------------------------------------------
template<typename IN_T>
__global__ __launch_bounds__(256, 4)
void conv_gemm_v2(const IN_T* __restrict__ X, const float* __restrict__ W,
                  const float* __restrict__ bias, float* __restrict__ Y) {
  const int g  = blockIdx.z;
  const int o0 = blockIdx.y << 7;         // 128-wide o tile
  const int n0 = blockIdx.x << 6;         // 64-wide n tile
  const int tid = threadIdx.x;
  const int tx = tid & 15, ty = tid >> 4;

  const IN_T* __restrict__ Xg = X + (size_t)g * CN;
  float* __restrict__ Yg = Y + (size_t)g * CN;

  __shared__ double wS[128][33];   // [o][c] pitch 33 -> 8-row stride = 2-way (free)
  __shared__ double xS[32][66];    // [c][n] pitch 66 -> conflict-free b-reads

  double acc[8][4] = {};

  float wst[16];
  float xst[8];

  auto loadW = [&](int c0) {
    #pragma unroll
    for (int i = 0; i < 4; ++i) {
      int L = i * 256 + tid;                     // 0..1023
      int o = L >> 3, c4 = (L & 7) << 2;
      const float4 v = *(const float4*)&W[(size_t)(o0 + o) * 512 + c0 + c4];
      wst[4*i+0] = v.x; wst[4*i+1] = v.y; wst[4*i+2] = v.z; wst[4*i+3] = v.w;
    }
  };
  auto loadX = [&](int c0) {
    #pragma unroll
    for (int i = 0; i < 2; ++i) {
      int L = i * 256 + tid;                     // 0..511
      int c = L >> 4, n4 = (L & 15) << 2;
      if constexpr (sizeof(IN_T) == 4) {
        const float4 v = *(const float4*)&Xg[(size_t)(c0 + c) * 256 + n0 + n4];
        xst[4*i+0] = v.x; xst[4*i+1] = v.y; xst[4*i+2] = v.z; xst[4*i+3] = v.w;
      } else {
        const uchar4 v = *(const uchar4*)&Xg[(size_t)(c0 + c) * 256 + n0 + n4];
        xst[4*i+0] = (float)v.x; xst[4*i+1] = (float)v.y;
        xst[4*i+2] = (float)v.z; xst[4*i+3] = (float)v.w;
      }
    }
  };
  auto storeTiles = [&]() {
    #pragma unroll
    for (int i = 0; i < 4; ++i) {
      int L = i * 256 + tid;
      int o = L >> 3, c4 = (L & 7) << 2;
      #pragma unroll
      for (int u = 0; u < 4; ++u) wS[o][c4 + u] = (double)wst[4*i+u];
    }
    #pragma unroll
    for (int i = 0; i < 2; ++i) {
      int L = i * 256 + tid;
      int c = L >> 4, n4 = (L & 15) << 2;
      #pragma unroll
      for (int u = 0; u < 4; ++u) xS[c][n4 + u] = (double)xst[4*i+u];
    }
  };

  loadW(0); loadX(0);

  for (int c0 = 0; c0 < 512; c0 += 32) {
    __syncthreads();                 // prior compute done before LDS overwrite
    storeTiles();
    __syncthreads();
    if (c0 + 32 < 512) { loadW(c0 + 32); loadX(c0 + 32); }

    #pragma unroll
    for (int k = 0; k < 32; ++k) {
      double b[4];
      #pragma unroll
      for (int j = 0; j < 4; ++j) b[j] = xS[k][tx + 16*j];
      #pragma unroll
      for (int i = 0; i < 8; ++i) {
        double a = wS[ty*8 + i][k];
        #pragma unroll
        for (int j = 0; j < 4; ++j) acc[i][j] = fma(a, b[j], acc[i][j]);
      }
    }
  }

  #pragma unroll
  for (int i = 0; i < 8; ++i) {
    const int o = o0 + ty*8 + i;
    const double bi = bias ? (double)bias[o] : 0.0;
    #pragma unroll
    for (int j = 0; j < 4; ++j)
      Yg[(size_t)o * 256 + n0 + tx + 16*j] = (float)(acc[i][j] + bi);
  }
}

// ---------------------------------------------------------------------------
// BN training-mode stats per channel over (T,B,N)=16384 values, fp64, 1 pass.
// ---------------------------------------------------------------------------
__global__ __launch_bounds__(256)
void bn_stats(const float* __restrict__ Y, const float* __restrict__ gamma,
              const float* __restrict__ beta, double* __restrict__ stats) {
  const int c = blockIdx.x;
  const int tid = threadIdx.x;
  __shared__ double redA[256];
  __shared__ double redB[256];

  double s = 0.0, s2 = 0.0;
  for (int g = 0; g < NG; ++g) {
    double y = (double)Y[((size_t)g * 512 + c) * 256 + tid];
    s += y; s2 += y * y;
  }
  redA[tid] = s; redB[tid] = s2; __syncthreads();
  for (int off = 128; off > 0; off >>= 1) {
    if (tid < off) { redA[tid] += redA[tid + off]; redB[tid] += redB[tid + off]; }
    __syncthreads();
  }
  if (tid == 0) {
    double m = redA[0] * (1.0 / 16384.0);
    double var = redB[0] * (1.0 / 16384.0) - m * m;
    double rstd = 1.0 / sqrt(var + 1e-5);
    double scale = (double)gamma[c] * rstd;
    stats[c] = scale;
    stats[512 + c] = (double)beta[c] - m * scale;
  }
}

// ---------------------------------------------------------------------------
// Multi-step LIF over T=4 (tau=2, hard reset). Optional BN affine first.
// ---------------------------------------------------------------------------
__global__ __launch_bounds__(256)
void lif_kernel(const float* __restrict__ Y, const double* __restrict__ stats,
                double thresh, unsigned char* __restrict__ s_u8,
                float* __restrict__ s_f32) {
  const size_t idx = (size_t)blockIdx.x * 256 + threadIdx.x;   // over B*C*N
  const int c = (int)((idx >> 8) & 511);
  double scale = 1.0, shift = 0.0;
  if (stats) { scale = stats[c]; shift = stats[512 + c]; }
  double v = 0.0;
  #pragma unroll
  for (int t = 0; t < 4; ++t) {
    double z = (double)Y[(size_t)t * BCN + idx] * scale + shift;
    v = v + (z - v) * 0.5;
    bool sp = (v - thresh) >= 0.0;
    if (s_u8) s_u8[(size_t)t * BCN + idx] = sp ? 1 : 0;
    else      s_f32[(size_t)t * BCN + idx] = sp ? 1.0f : 0.0f;
    if (sp) v = 0.0;
  }
}

// ---------------------------------------------------------------------------
// kv[d][e] = sum_n k[h*64+d][n] * v[h*64+e][n]  (integer counts, exact)
// ---------------------------------------------------------------------------
__global__ __launch_bounds__(256)
void attn_kv(const unsigned char* __restrict__ sk, const unsigned char* __restrict__ sv,
             float* __restrict__ kv) {
  const int blk = blockIdx.x;                       // g*8 + h
  const int tid = threadIdx.x;
  const size_t base = ((size_t)(blk >> 3) * 512 + (size_t)(blk & 7) * 64) * 256;
  __shared__ unsigned char kS[64][256];
  __shared__ unsigned char vS[64][256];
  const uint32_t* K32 = (const uint32_t*)(sk + base);
  const uint32_t* V32 = (const uint32_t*)(sv + base);
  uint32_t* kS32 = (uint32_t*)&kS[0][0];
  uint32_t* vS32 = (uint32_t*)&vS[0][0];
  #pragma unroll
  for (int i = 0; i < 16; ++i) {
    kS32[i * 256 + tid] = K32[i * 256 + tid];
    vS32[i * 256 + tid] = V32[i * 256 + tid];
  }
  __syncthreads();
  const int d0 = (tid >> 4) << 2, e0 = (tid & 15) << 2;
  int acc[4][4] = {};
  for (int n = 0; n < 256; ++n) {
    int k_[4], v_[4];
    #pragma unroll
    for (int i = 0; i < 4; ++i) k_[i] = kS[d0 + i][n];
    #pragma unroll
    for (int j = 0; j < 4; ++j) v_[j] = vS[e0 + j][n];
    #pragma unroll
    for (int i = 0; i < 4; ++i)
      #pragma unroll
      for (int j = 0; j < 4; ++j) acc[i][j] += k_[i] * v_[j];
  }
  float* KV = kv + (size_t)blk * 4096;
  #pragma unroll
  for (int i = 0; i < 4; ++i)
    #pragma unroll
    for (int j = 0; j < 4; ++j)
      KV[(d0 + i) * 64 + e0 + j] = (float)acc[i][j];
}

// ---------------------------------------------------------------------------
// attn[h*64+e][n] = 0.125 * sum_d q[h*64+d][n] * kv[d][e]  (exact in fp32)
// ---------------------------------------------------------------------------
__global__ __launch_bounds__(256)
void attn_qkv(const unsigned char* __restrict__ sq, const float* __restrict__ kv,
              float* __restrict__ attn) {
  const int blk = blockIdx.x;
  const int tid = threadIdx.x;
  const size_t base = ((size_t)(blk >> 3) * 512 + (size_t)(blk & 7) * 64) * 256;
  __shared__ unsigned char qS[64][256];
  __shared__ float kvS[64][64];
  const uint32_t* Q32 = (const uint32_t*)(sq + base);
  uint32_t* qS32 = (uint32_t*)&qS[0][0];
  const float* KV = kv + (size_t)blk * 4096;
  #pragma unroll
  for (int i = 0; i < 16; ++i) {
    qS32[i * 256 + tid] = Q32[i * 256 + tid];
    (&kvS[0][0])[i * 256 + tid] = KV[i * 256 + tid];
  }
  __syncthreads();
  const int n = tid;
  float acc[64];
  #pragma unroll
  for (int e = 0; e < 64; ++e) acc[e] = 0.0f;
  for (int d = 0; d < 64; ++d) {
    float qf = (float)qS[d][n];
    #pragma unroll
    for (int e = 0; e < 64; ++e) acc[e] = fmaf(qf, kvS[d][e], acc[e]);
  }
  float* A = attn + base;
  #pragma unroll
  for (int e = 0; e < 64; ++e) A[(size_t)e * 256 + n] = acc[e] * 0.125f;
}

// ---------------------------------------------------------------------------
extern "C" void kernel_launch(void* const* d_in, const int* in_sizes, int n_in,
                              void* d_out, int out_size, void* d_ws, size_t ws_size,
                              hipStream_t stream) {
  const float* x          = (const float*)d_in[0];
  const float* q_w        = (const float*)d_in[1];
  const float* q_gamma    = (const float*)d_in[2];
  const float* q_beta     = (const float*)d_in[3];
  const float* k_w        = (const float*)d_in[4];
  const float* k_gamma    = (const float*)d_in[5];
  const float* k_beta     = (const float*)d_in[6];
  const float* v_w        = (const float*)d_in[7];
  const float* v_gamma    = (const float*)d_in[8];
  const float* v_beta     = (const float*)d_in[9];
  const float* proj_w     = (const float*)d_in[10];
  const float* proj_b     = (const float*)d_in[11];
  const float* proj_gamma = (const float*)d_in[12];
  const float* proj_beta  = (const float*)d_in[13];

  const size_t YB = (size_t)4 * BCN * sizeof(float);      // 33,554,432
  const size_t SB = (size_t)4 * BCN;                      //  8,388,608
  if (ws_size < YB + 5 * SB + 1024 * sizeof(double)) return;

  char* ws = (char*)d_ws;
  float* yA           = (float*)ws;                       // conv out / attn vals / proj out
  unsigned char* s_q  = (unsigned char*)(ws + YB);
  unsigned char* s_k  = s_q + SB;
  unsigned char* s_v  = s_k + SB;
  unsigned char* s_at = s_v + SB;
  float* kvb          = (float*)(ws + YB + 4 * SB);
  double* stats       = (double*)(ws + YB + 5 * SB);

  dim3 gGemm(4, 4, NG);   // n-tiles(64), o-tiles(128), groups

  const float* bw[3] = {q_w, k_w, v_w};
  const float* bg[3] = {q_gamma, k_gamma, v_gamma};
  const float* bb[3] = {q_beta, k_beta, v_beta};
  unsigned char* bs[3] = {s_q, s_k, s_v};

  for (int i = 0; i < 3; ++i) {
    conv_gemm_v2<float><<<gGemm, 256, 0, stream>>>(x, bw[i], nullptr, yA);
    bn_stats<<<512, 256, 0, stream>>>(yA, bg[i], bb[i], stats);
    lif_kernel<<<8192, 256, 0, stream>>>(yA, stats, 1.0, bs[i], nullptr);
  }

  attn_kv<<<512, 256, 0, stream>>>(s_k, s_v, kvb);
  attn_qkv<<<512, 256, 0, stream>>>(s_q, kvb, yA);
  lif_kernel<<<8192, 256, 0, stream>>>(yA, nullptr, 0.5, s_at, nullptr);

  conv_gemm_v2<unsigned char><<<gGemm, 256, 0, stream>>>(s_at, proj_w, proj_b, yA);
  bn_stats<<<512, 256, 0, stream>>>(yA, proj_gamma, proj_beta, stats);
  lif_kernel<<<8192, 256, 0, stream>>>(yA, stats, 1.0, nullptr, (float*)d_out);
}